// Round 5
// baseline (1195.687 us; speedup 1.0000x reference)
//
#include <hip/hip_runtime.h>
#include <cstdint>

#define Bn 4
#define DIMn 256
#define Ln 4096
#define C2n 512
#define CBn 256
#define NHn 8
#define HDn 32
#define WINn 512
#define Mtot (Bn * Ln)

using bf16x8 = __attribute__((ext_vector_type(8))) short;
using f32x4 = __attribute__((ext_vector_type(4))) float;

static constexpr float kScale = 0.17677669529663687f;  // 32^-0.5
static constexpr float kEps = 1e-5f;

__device__ __forceinline__ ushort f2bf(float f) {
  union {
    float f;
    unsigned u;
  } v;
  v.f = f;
  unsigned r = v.u + 0x7FFFu + ((v.u >> 16) & 1u);
  return (ushort)(r >> 16);
}

__device__ __forceinline__ float bf2f(ushort u) {
  union {
    unsigned u;
    float f;
  } v;
  v.u = (unsigned)u << 16;
  return v.f;
}

__device__ __forceinline__ void gload16(const void* g, void* l) {
  __builtin_amdgcn_global_load_lds(
      (const __attribute__((address_space(1))) unsigned*)g,
      (__attribute__((address_space(3))) unsigned*)l, 16, 0, 0);
}

enum GMode { M_EMBED = 0, M_QKV = 1, M_PROJ = 2, M_OUT = 3, M_VOUT = 4 };

// ---------------------------------------------------------------------------
// R1's proven f32 vector GEMM (verbatim) — drives Output 0.
// ---------------------------------------------------------------------------
template <int MODE, int K>
__global__ __launch_bounds__(256) void gemm_k(
    const float* __restrict__ A, const float* __restrict__ Bw,
    float* __restrict__ C, const float* __restrict__ mu,
    const float* __restrict__ rstd, const float* __restrict__ g1,
    const float* __restrict__ b1, const float* __restrict__ bias,
    float* __restrict__ resid) {
  constexpr int NFULL = (MODE == M_EMBED) ? 512
                        : (MODE == M_QKV) ? 1536
                        : (MODE == M_PROJ) ? 512
                                           : 256;
  constexpr int NT = NFULL / 64;
  constexpr int LDC = (MODE == M_QKV) ? 1536 : 512;

  __shared__ float As[16][68];
  __shared__ float Bs[16][68];

  const int tid = threadIdx.x;
  const int tileM = blockIdx.x / NT;
  const int tileN = blockIdx.x % NT;
  const int m0 = tileM * 64;
  const int n0 = tileN * 64;
  const int ty = tid >> 4;
  const int tx = tid & 15;

  float acc[4][4] = {};

  float lnmu[4] = {}, lnrs[4] = {};
  if (MODE == M_QKV) {
#pragma unroll
    for (int i = 0; i < 4; ++i) {
      const int mg = m0 + (tid >> 4) + i * 16;
      lnmu[i] = mu[mg];
      lnrs[i] = rstd[mg];
    }
  }

  for (int k0 = 0; k0 < K; k0 += 16) {
    if (MODE == M_EMBED) {
      const int ml = tid & 63;
      const int kb = tid >> 6;
      const int mg = m0 + ml;
      const int bi = mg >> 12;
      const int l = mg & (Ln - 1);
#pragma unroll
      for (int i = 0; i < 4; ++i) {
        const int kl = kb * 4 + i;
        As[kl][ml] =
            A[(size_t)bi * (DIMn * Ln) + (size_t)(k0 + kl) * Ln + l];
      }
    } else {
      const int kl = tid & 15;
      const int mb = tid >> 4;
#pragma unroll
      for (int i = 0; i < 4; ++i) {
        const int ml = mb + i * 16;
        const int mg = m0 + ml;
        float v;
        if (MODE == M_QKV) {
          const int kg = k0 + kl;
          const float raw = A[(size_t)mg * 512 + kg];
          v = (raw - lnmu[i]) * lnrs[i] * g1[kg] + b1[kg];
        } else if (MODE == M_PROJ) {
          v = A[(size_t)mg * 1536 + (k0 + kl)];
        } else if (MODE == M_OUT) {
          v = A[(size_t)mg * 512 + (k0 + kl)];
        } else {
          v = A[(size_t)mg * 1536 + 1024 + (k0 + kl)];
        }
        As[kl][ml] = v;
      }
    }
    {
      const int nl = tid & 63;
      const int kb = tid >> 6;
#pragma unroll
      for (int i = 0; i < 4; ++i) {
        const int kl = kb * 4 + i;
        Bs[kl][nl] = Bw[(size_t)(k0 + kl) * NFULL + n0 + nl];
      }
    }
    __syncthreads();
#pragma unroll
    for (int kk = 0; kk < 16; ++kk) {
      const float4 a4 = *(const float4*)&As[kk][ty * 4];
      const float4 b4 = *(const float4*)&Bs[kk][tx * 4];
      const float av[4] = {a4.x, a4.y, a4.z, a4.w};
      const float bv[4] = {b4.x, b4.y, b4.z, b4.w};
#pragma unroll
      for (int i = 0; i < 4; ++i)
#pragma unroll
        for (int j = 0; j < 4; ++j)
          acc[i][j] = fmaf(av[i], bv[j], acc[i][j]);
    }
    __syncthreads();
  }

  if constexpr (MODE == M_OUT || MODE == M_VOUT) {
    __shared__ float Cs[64][68];
#pragma unroll
    for (int i = 0; i < 4; ++i)
      *(float4*)&Cs[ty * 4 + i][tx * 4] =
          make_float4(acc[i][0], acc[i][1], acc[i][2], acc[i][3]);
    __syncthreads();
    const int ll = tid & 63;
    const int nb = tid >> 6;
    const int mg = m0 + ll;
    const int bi = mg >> 12;
    const int l = mg & (Ln - 1);
    const size_t base = (MODE == M_VOUT ? (size_t)Bn * DIMn * Ln : 0) +
                        (size_t)bi * (DIMn * Ln) + l;
#pragma unroll
    for (int i = 0; i < 16; ++i) {
      const int nl = nb + i * 4;
      C[base + (size_t)(n0 + nl) * Ln] = Cs[ll][nl];
    }
  } else if constexpr (MODE == M_PROJ) {
#pragma unroll
    for (int i = 0; i < 4; ++i) {
      const size_t idx = (size_t)(m0 + ty * 4 + i) * 512 + n0 + tx * 4;
      float4 r = *(float4*)&resid[idx];
      const float4 bb = *(const float4*)&bias[n0 + tx * 4];
      r.x += acc[i][0] + bb.x;
      r.y += acc[i][1] + bb.y;
      r.z += acc[i][2] + bb.z;
      r.w += acc[i][3] + bb.w;
      *(float4*)&resid[idx] = r;
    }
  } else {
#pragma unroll
    for (int i = 0; i < 4; ++i) {
      const size_t idx = (size_t)(m0 + ty * 4 + i) * LDC + n0 + tx * 4;
      *(float4*)&C[idx] =
          make_float4(acc[i][0], acc[i][1], acc[i][2], acc[i][3]);
    }
  }
}

__global__ __launch_bounds__(128) void ln_stats(const float* __restrict__ x2,
                                                float* __restrict__ mu,
                                                float* __restrict__ rstd) {
  const int r = blockIdx.x;
  const int t = threadIdx.x;
  const float4 v = *(const float4*)&x2[(size_t)r * 512 + t * 4];
  float s = v.x + v.y + v.z + v.w;
  float s2 = v.x * v.x + v.y * v.y + v.z * v.z + v.w * v.w;
#pragma unroll
  for (int off = 32; off > 0; off >>= 1) {
    s += __shfl_down(s, off);
    s2 += __shfl_down(s2, off);
  }
  __shared__ float ps[2], ps2[2];
  if ((t & 63) == 0) {
    ps[t >> 6] = s;
    ps2[t >> 6] = s2;
  }
  __syncthreads();
  if (t == 0) {
    const float S = ps[0] + ps[1];
    const float S2 = ps2[0] + ps2[1];
    const float m = S * (1.0f / 512.0f);
    const float var = S2 * (1.0f / 512.0f) - m * m;
    mu[r] = m;
    rstd[r] = rsqrtf(var + kEps);
  }
}

__global__ __launch_bounds__(256) void attn_k(float* __restrict__ qkv,
                                              const float* __restrict__ cw0,
                                              const float* __restrict__ cb0,
                                              const float* __restrict__ cw1,
                                              const float* __restrict__ cb1) {
  __shared__ float Ks[WINn][HDn];
  __shared__ float Vs[WINn][HDn];

  const int blk = blockIdx.x;
  const int branch = blk >> 8;
  const int b = (blk >> 6) & 3;
  const int win = (blk >> 3) & 7;
  const int head = blk & 7;
  const int tid = threadIdx.x;
  const int qcol = branch * CBn + head * HDn;

  auto tok2l = [&](int p) -> int {
    return branch == 0 ? ((p >> 3) * 64 + win * 8 + (p & 7))
                       : (win * 512 + p);
  };

#pragma unroll
  for (int rr = 0; rr < 2; ++rr) {
    const int p = tid + rr * 256;
    const size_t row = ((size_t)b * Ln + tok2l(p)) * 1536;
#pragma unroll
    for (int d4 = 0; d4 < 8; ++d4) {
      *(float4*)&Ks[p][d4 * 4] =
          *(const float4*)&qkv[row + 512 + qcol + d4 * 4];
      *(float4*)&Vs[p][d4 * 4] =
          *(const float4*)&qkv[row + 1024 + qcol + d4 * 4];
    }
  }

  float q0[HDn], q1[HDn];
  const int p0 = tid, p1 = tid + 256;
  const size_t row0 = ((size_t)b * Ln + tok2l(p0)) * 1536 + qcol;
  const size_t row1 = ((size_t)b * Ln + tok2l(p1)) * 1536 + qcol;
#pragma unroll
  for (int d4 = 0; d4 < 8; ++d4) {
    const float4 a = *(const float4*)&qkv[row0 + d4 * 4];
    q0[d4 * 4 + 0] = a.x * kScale;
    q0[d4 * 4 + 1] = a.y * kScale;
    q0[d4 * 4 + 2] = a.z * kScale;
    q0[d4 * 4 + 3] = a.w * kScale;
    const float4 c = *(const float4*)&qkv[row1 + d4 * 4];
    q1[d4 * 4 + 0] = c.x * kScale;
    q1[d4 * 4 + 1] = c.y * kScale;
    q1[d4 * 4 + 2] = c.z * kScale;
    q1[d4 * 4 + 3] = c.w * kScale;
  }
  __syncthreads();

  float acc0[HDn] = {}, acc1[HDn] = {};
  float den0 = 0.0f, den1 = 0.0f;
  for (int j = 0; j < WINn; ++j) {
    float s0a = 0, s0b = 0, s1a = 0, s1b = 0;
#pragma unroll
    for (int d4 = 0; d4 < 8; ++d4) {
      const float4 kv = *(const float4*)&Ks[j][d4 * 4];
      if (d4 & 1) {
        s0b = fmaf(q0[d4 * 4 + 0], kv.x, s0b);
        s0b = fmaf(q0[d4 * 4 + 1], kv.y, s0b);
        s0b = fmaf(q0[d4 * 4 + 2], kv.z, s0b);
        s0b = fmaf(q0[d4 * 4 + 3], kv.w, s0b);
        s1b = fmaf(q1[d4 * 4 + 0], kv.x, s1b);
        s1b = fmaf(q1[d4 * 4 + 1], kv.y, s1b);
        s1b = fmaf(q1[d4 * 4 + 2], kv.z, s1b);
        s1b = fmaf(q1[d4 * 4 + 3], kv.w, s1b);
      } else {
        s0a = fmaf(q0[d4 * 4 + 0], kv.x, s0a);
        s0a = fmaf(q0[d4 * 4 + 1], kv.y, s0a);
        s0a = fmaf(q0[d4 * 4 + 2], kv.z, s0a);
        s0a = fmaf(q0[d4 * 4 + 3], kv.w, s0a);
        s1a = fmaf(q1[d4 * 4 + 0], kv.x, s1a);
        s1a = fmaf(q1[d4 * 4 + 1], kv.y, s1a);
        s1a = fmaf(q1[d4 * 4 + 2], kv.z, s1a);
        s1a = fmaf(q1[d4 * 4 + 3], kv.w, s1a);
      }
    }
    const float e0 = __expf(s0a + s0b);
    const float e1 = __expf(s1a + s1b);
    den0 += e0;
    den1 += e1;
#pragma unroll
    for (int d4 = 0; d4 < 8; ++d4) {
      const float4 vv = *(const float4*)&Vs[j][d4 * 4];
      acc0[d4 * 4 + 0] = fmaf(e0, vv.x, acc0[d4 * 4 + 0]);
      acc0[d4 * 4 + 1] = fmaf(e0, vv.y, acc0[d4 * 4 + 1]);
      acc0[d4 * 4 + 2] = fmaf(e0, vv.z, acc0[d4 * 4 + 2]);
      acc0[d4 * 4 + 3] = fmaf(e0, vv.w, acc0[d4 * 4 + 3]);
      acc1[d4 * 4 + 0] = fmaf(e1, vv.x, acc1[d4 * 4 + 0]);
      acc1[d4 * 4 + 1] = fmaf(e1, vv.y, acc1[d4 * 4 + 1]);
      acc1[d4 * 4 + 2] = fmaf(e1, vv.z, acc1[d4 * 4 + 2]);
      acc1[d4 * 4 + 3] = fmaf(e1, vv.w, acc1[d4 * 4 + 3]);
    }
  }

  const float* cw = branch ? cw1 : cw0;
  const float* cb = branch ? cb1 : cb0;
  const int Hs = branch ? 8 : 64;
  const int Ws = branch ? 64 : 8;
  const float inv0 = 1.0f / den0;
  const float inv1 = 1.0f / den1;

  auto write_row = [&](int p, float inv, const float(&ac)[HDn]) {
    const int hl = branch ? (p >> 6) : (p >> 3);
    const int wl = branch ? (p & 63) : (p & 7);
    const size_t orow = ((size_t)b * Ln + tok2l(p)) * 1536 + qcol;
#pragma unroll
    for (int d4 = 0; d4 < 8; ++d4) {
      float ov[4];
#pragma unroll
      for (int u = 0; u < 4; ++u) {
        const int d = d4 * 4 + u;
        const int c = head * HDn + d;
        float le = cb[c];
#pragma unroll
        for (int dh = -1; dh <= 1; ++dh) {
          const int hh = hl + dh;
          const bool hok = (hh >= 0) && (hh < Hs);
#pragma unroll
          for (int dw = -1; dw <= 1; ++dw) {
            const int ww = wl + dw;
            const bool ok = hok && (ww >= 0) && (ww < Ws);
            const int pp = ok ? (hh * Ws + ww) : 0;
            const float vv = ok ? Vs[pp][d] : 0.0f;
            le = fmaf(vv, cw[c * 9 + (dh + 1) * 3 + (dw + 1)], le);
          }
        }
        ov[u] = fmaf(ac[d], inv, le);
      }
      *(float4*)&qkv[orow + d4 * 4] =
          make_float4(ov[0], ov[1], ov[2], ov[3]);
    }
  };
  write_row(p0, inv0, acc0);
  write_row(p1, inv1, acc1);
}

// ---------------------------------------------------------------------------
// EXPERIMENT (Output 1): R3-verbatim bf16 v-chain under test.
// ---------------------------------------------------------------------------
enum { G_EMBED = 0, G_QKV = 1, G_PROJ = 2, G_OUTT = 3 };

template <int MODE, int ND, int KD, int LDB>
__global__ __launch_bounds__(256) void gemm_bf(
    const ushort* __restrict__ A, const ushort* __restrict__ Bt,
    float* __restrict__ C, const ushort* __restrict__ resid,
    const float* __restrict__ bias, ushort* __restrict__ aux,
    size_t outBase) {
  constexpr int NT = ND / 128;
  __shared__ ushort As[128 * 64];
  __shared__ ushort Bs[128 * 64];

  const int tid = threadIdx.x;
  const int wid = tid >> 6;
  const int lane = tid & 63;
  const int m0 = (blockIdx.x / NT) * 128;
  const int n0 = (blockIdx.x % NT) * 128;

  const int gs = (wid < 2) ? KD : LDB;
  const ushort* gsrc = (wid < 2)
                           ? A + (size_t)(m0 + (wid & 1) * 64) * KD
                           : Bt + (size_t)(n0 + (wid & 1) * 64) * LDB;
  ushort* lbase = (wid < 2 ? As : Bs) + (wid & 1) * (64 * 64);
  const int r8 = lane >> 3;
  const int c8 = lane & 7;

  f32x4 acc[4][4];
#pragma unroll
  for (int i = 0; i < 4; ++i)
#pragma unroll
    for (int j = 0; j < 4; ++j) acc[i][j] = (f32x4){0.f, 0.f, 0.f, 0.f};

  const int wm = (wid & 1) * 64;
  const int wn = (wid >> 1) * 64;
  const int lr = lane & 15;
  const int kq = lane >> 4;

  for (int k0 = 0; k0 < KD; k0 += 64) {
    __syncthreads();
#pragma unroll
    for (int i = 0; i < 8; ++i) {
      const ushort* g = gsrc + (size_t)(i * 8 + r8) * gs + (k0 + c8 * 8);
      gload16(g, lbase + i * 512);
    }
    __syncthreads();
#pragma unroll
    for (int kk = 0; kk < 2; ++kk) {
      bf16x8 af[4], bfr[4];
#pragma unroll
      for (int i = 0; i < 4; ++i)
        af[i] = *(const bf16x8*)(As + (wm + i * 16 + lr) * 64 +
                                 (kk * 4 + kq) * 8);
#pragma unroll
      for (int j = 0; j < 4; ++j)
        bfr[j] = *(const bf16x8*)(Bs + (wn + j * 16 + lr) * 64 +
                                  (kk * 4 + kq) * 8);
#pragma unroll
      for (int i = 0; i < 4; ++i)
#pragma unroll
        for (int j = 0; j < 4; ++j)
          acc[i][j] = __builtin_amdgcn_mfma_f32_16x16x32_bf16(
              af[i], bfr[j], acc[i][j], 0, 0, 0);
    }
  }

#pragma unroll
  for (int i = 0; i < 4; ++i) {
#pragma unroll
    for (int j = 0; j < 4; ++j) {
#pragma unroll
      for (int t = 0; t < 4; ++t) {
        const int mr = m0 + wm + i * 16 + kq * 4 + t;
        const int nc = n0 + wn + j * 16 + lr;
        const float val = acc[i][j][t];
        if constexpr (MODE == G_EMBED) {
          aux[(size_t)mr * 512 + nc] = f2bf(val);
        } else if constexpr (MODE == G_QKV) {
          aux[(size_t)mr * 1536 + nc] = f2bf(val);
        } else if constexpr (MODE == G_PROJ) {
          const float v2 =
              val + bf2f(resid[(size_t)mr * 512 + nc]) + bias[nc];
          aux[(size_t)mr * 512 + nc] = f2bf(v2);
        } else {
          C[outBase + ((size_t)(nc >> 12)) * ((size_t)DIMn * Ln) +
            (size_t)mr * Ln + (nc & 4095)] = val;
        }
      }
    }
  }
}

__global__ __launch_bounds__(256) void cvt_w(const float* __restrict__ in,
                                             ushort* __restrict__ out,
                                             int lgK, int N) {
  const int t = blockIdx.x * 256 + threadIdx.x;
  const int K = 1 << lgK;
  const int n = t >> lgK;
  const int k = t & (K - 1);
  out[t] = f2bf(in[(size_t)k * N + n]);
}

__global__ __launch_bounds__(256) void cvt_x(const float* __restrict__ x,
                                             ushort* __restrict__ xe) {
  __shared__ ushort tile[64][65];
  const int blk = blockIdx.x;
  const int lt = blk & 63;
  const int ct = (blk >> 6) & 3;
  const int b = blk >> 8;
  const int l0 = lt * 64, c0 = ct * 64;
  const int t = threadIdx.x;
  const int lanel = t & 63;
  const int grp = t >> 6;
#pragma unroll
  for (int it = 0; it < 16; ++it) {
    const int c = grp * 16 + it;
    tile[c][lanel] =
        f2bf(x[(size_t)b * (DIMn * Ln) + (size_t)(c0 + c) * Ln + l0 + lanel]);
  }
  __syncthreads();
#pragma unroll
  for (int it = 0; it < 16; ++it) {
    const int l = grp * 16 + it;
    xe[((size_t)b * Ln + l0 + l) * 256 + c0 + lanel] = tile[lanel][l];
  }
}

__global__ __launch_bounds__(128) void ln_fuse(const ushort* __restrict__ x2,
                                               const float* __restrict__ g1,
                                               const float* __restrict__ b1,
                                               ushort* __restrict__ xln) {
  const int row = blockIdx.x;
  const int t = threadIdx.x;
  const ushort4 u4 = *(const ushort4*)&x2[(size_t)row * 512 + t * 4];
  float v[4] = {bf2f(u4.x), bf2f(u4.y), bf2f(u4.z), bf2f(u4.w)};
  float s = v[0] + v[1] + v[2] + v[3];
  float s2 = v[0] * v[0] + v[1] * v[1] + v[2] * v[2] + v[3] * v[3];
#pragma unroll
  for (int off = 32; off > 0; off >>= 1) {
    s += __shfl_down(s, off);
    s2 += __shfl_down(s2, off);
  }
  __shared__ float red[4];
  if ((t & 63) == 0) {
    red[t >> 6] = s;
    red[2 + (t >> 6)] = s2;
  }
  __syncthreads();
  const float S = red[0] + red[1];
  const float S2 = red[2] + red[3];
  const float mu = S * (1.f / 512.f);
  const float rs = rsqrtf(S2 * (1.f / 512.f) - mu * mu + kEps);
  const float4 g = *(const float4*)&g1[t * 4];
  const float4 bb = *(const float4*)&b1[t * 4];
  ushort4 o;
  o.x = f2bf((v[0] - mu) * rs * g.x + bb.x);
  o.y = f2bf((v[1] - mu) * rs * g.y + bb.y);
  o.z = f2bf((v[2] - mu) * rs * g.z + bb.z);
  o.w = f2bf((v[3] - mu) * rs * g.w + bb.w);
  *(ushort4*)&xln[(size_t)row * 512 + t * 4] = o;
}

// ---------------------------------------------------------------------------
extern "C" void kernel_launch(void* const* d_in, const int* in_sizes, int n_in,
                              void* d_out, int out_size, void* d_ws,
                              size_t ws_size, hipStream_t stream) {
  const float* x = (const float*)d_in[0];
  const float* w_embed = (const float*)d_in[1];
  const float* g1 = (const float*)d_in[2];
  const float* b1 = (const float*)d_in[3];
  const float* w_qkv = (const float*)d_in[4];
  const float* cw0 = (const float*)d_in[5];
  const float* cb0 = (const float*)d_in[6];
  const float* cw1 = (const float*)d_in[7];
  const float* cb1 = (const float*)d_in[8];
  const float* w_proj = (const float*)d_in[9];
  const float* b_proj = (const float*)d_in[10];
  const float* w_out = (const float*)d_in[11];
  float* out = (float*)d_out;

  // R1 carve (proven 134.4 MB peak): x2 f32 | qkv f32 | mu | rstd.
  float* x2 = (float*)d_ws;
  float* qkv = x2 + (size_t)Mtot * C2n;
  float* mu = qkv + (size_t)Mtot * 3 * C2n;
  float* rstd = mu + Mtot;

  // bf16 v-chain buffers live INSIDE the f32 qkv region (dead after PROJ):
  // xe [M][256] | x2bf [M][512] | xln [M][512] | qkvbf [M][1536] | weights
  // total 94.4 MB <= 100.7 MB region.
  ushort* xe = (ushort*)qkv;
  ushort* x2bf = xe + (size_t)Mtot * 256;
  ushort* xln = x2bf + (size_t)Mtot * 512;
  ushort* qkvbf = xln + (size_t)Mtot * 512;
  ushort* we_t = qkvbf + (size_t)Mtot * 1536;
  ushort* wq_t = we_t + 512 * 256;
  ushort* wo_t = wq_t + 1536 * 512;

  const int M = Mtot;

  // ---- Output 0: verbatim R1 f32 pipeline ----
  gemm_k<M_EMBED, 256><<<dim3(M / 64 * (512 / 64)), 256, 0, stream>>>(
      x, w_embed, x2, nullptr, nullptr, nullptr, nullptr, nullptr, nullptr);
  ln_stats<<<dim3(M), 128, 0, stream>>>(x2, mu, rstd);
  gemm_k<M_QKV, 512><<<dim3(M / 64 * (1536 / 64)), 256, 0, stream>>>(
      x2, w_qkv, qkv, mu, rstd, g1, b1, nullptr, nullptr);
  attn_k<<<dim3(512), 256, 0, stream>>>(qkv, cw0, cb0, cw1, cb1);
  gemm_k<M_PROJ, 512><<<dim3(M / 64 * (512 / 64)), 256, 0, stream>>>(
      qkv, w_proj, nullptr, nullptr, nullptr, nullptr, nullptr, b_proj, x2);
  gemm_k<M_OUT, 512><<<dim3(M / 64 * (256 / 64)), 256, 0, stream>>>(
      x2, w_out, out, nullptr, nullptr, nullptr, nullptr, nullptr, nullptr);

  // ---- Output 1: R3-verbatim bf16 v-chain (qkv f32 region now dead) ----
  cvt_x<<<dim3(1024), 256, 0, stream>>>(x, xe);
  cvt_w<<<dim3(512 * 256 / 256), 256, 0, stream>>>(w_embed, we_t, 8, 512);
  cvt_w<<<dim3(1536 * 512 / 256), 256, 0, stream>>>(w_qkv, wq_t, 9, 1536);
  cvt_w<<<dim3(256 * 512 / 256), 256, 0, stream>>>(w_out, wo_t, 9, 256);
  // x2bf = xe @ we_t  (EMBED, KD=256)
  gemm_bf<G_EMBED, 512, 256, 256><<<dim3(128 * 4), 256, 0, stream>>>(
      xe, we_t, nullptr, nullptr, nullptr, x2bf, 0);
  // xln = LN(x2bf)
  ln_fuse<<<dim3(M), 128, 0, stream>>>(x2bf, g1, b1, xln);
  // qkvbf = xln @ wq_t  (QKV, ND=1536)
  gemm_bf<G_QKV, 1536, 512, 512><<<dim3(128 * 12), 256, 0, stream>>>(
      xln, wq_t, nullptr, nullptr, nullptr, qkvbf, 0);
  // vout = wo_t @ v^T  (OUTT, LDB=1536, v in-place in qkvbf)
  gemm_bf<G_OUTT, Mtot, 512, 1536><<<dim3(2 * 128), 256, 0, stream>>>(
      wo_t, qkvbf + 1024, out, nullptr, nullptr, nullptr,
      (size_t)Bn * DIMn * Ln);
}

// Round 7
// 499.250 us; speedup vs baseline: 2.3950x; 2.3950x over previous
//
#include <hip/hip_runtime.h>
#include <cstdint>

#define Bn 4
#define DIMn 256
#define Ln 4096
#define C2n 512
#define CBn 256
#define HDn 32
#define Mtot (Bn * Ln)

using bf16x8 = __attribute__((ext_vector_type(8))) short;
using f32x4 = __attribute__((ext_vector_type(4))) float;

static constexpr float kScale = 0.17677669529663687f;  // 32^-0.5
static constexpr float kEps = 1e-5f;

__device__ __forceinline__ ushort f2bf(float f) {
  union {
    float f;
    unsigned u;
  } v;
  v.f = f;
  unsigned r = v.u + 0x7FFFu + ((v.u >> 16) & 1u);
  return (ushort)(r >> 16);
}

__device__ __forceinline__ float bf2f(ushort u) {
  union {
    unsigned u;
    float f;
  } v;
  v.u = (unsigned)u << 16;
  return v.f;
}

__device__ __forceinline__ void gload16(const void* g, void* l) {
  __builtin_amdgcn_global_load_lds(
      (const __attribute__((address_space(1))) unsigned*)g,
      (__attribute__((address_space(3))) unsigned*)l, 16, 0, 0);
}

// ---------------------------------------------------------------------------
// bf16 MFMA GEMM, m97 structure (HW-verified R4/R5): 128x128 tile, BK=64,
// 4 waves 2x2 of 64x64, 16x16x32 MFMA, linear LDS, gload16 staging.
// A [.][KD] bf16 (LDA==KD); Bt [ND][LDB] bf16 (B^T, K-fastest).
// ---------------------------------------------------------------------------
enum { G_EMBED = 0, G_QKV = 1, G_PROJ = 2, G_OUTT = 3 };

template <int MODE, int ND, int KD, int LDB>
__global__ __launch_bounds__(256) void gemm_bf(
    const ushort* __restrict__ A, const ushort* __restrict__ Bt,
    float* __restrict__ C, const ushort* __restrict__ resid,
    const float* __restrict__ bias, ushort* __restrict__ aux,
    size_t outBase) {
  constexpr int NT = ND / 128;
  __shared__ ushort As[128 * 64];
  __shared__ ushort Bs[128 * 64];

  const int tid = threadIdx.x;
  const int wid = tid >> 6;
  const int lane = tid & 63;
  const int m0 = (blockIdx.x / NT) * 128;
  const int n0 = (blockIdx.x % NT) * 128;

  const int gs = (wid < 2) ? KD : LDB;
  const ushort* gsrc = (wid < 2)
                           ? A + (size_t)(m0 + (wid & 1) * 64) * KD
                           : Bt + (size_t)(n0 + (wid & 1) * 64) * LDB;
  ushort* lbase = (wid < 2 ? As : Bs) + (wid & 1) * (64 * 64);
  const int r8 = lane >> 3;
  const int c8 = lane & 7;

  f32x4 acc[4][4];
#pragma unroll
  for (int i = 0; i < 4; ++i)
#pragma unroll
    for (int j = 0; j < 4; ++j) acc[i][j] = (f32x4){0.f, 0.f, 0.f, 0.f};

  const int wm = (wid & 1) * 64;
  const int wn = (wid >> 1) * 64;
  const int lr = lane & 15;
  const int kq = lane >> 4;

  for (int k0 = 0; k0 < KD; k0 += 64) {
    __syncthreads();
#pragma unroll
    for (int i = 0; i < 8; ++i) {
      const ushort* g = gsrc + (size_t)(i * 8 + r8) * gs + (k0 + c8 * 8);
      gload16(g, lbase + i * 512);
    }
    __syncthreads();
#pragma unroll
    for (int kk = 0; kk < 2; ++kk) {
      bf16x8 af[4], bfr[4];
#pragma unroll
      for (int i = 0; i < 4; ++i)
        af[i] = *(const bf16x8*)(As + (wm + i * 16 + lr) * 64 +
                                 (kk * 4 + kq) * 8);
#pragma unroll
      for (int j = 0; j < 4; ++j)
        bfr[j] = *(const bf16x8*)(Bs + (wn + j * 16 + lr) * 64 +
                                  (kk * 4 + kq) * 8);
#pragma unroll
      for (int i = 0; i < 4; ++i)
#pragma unroll
        for (int j = 0; j < 4; ++j)
          acc[i][j] = __builtin_amdgcn_mfma_f32_16x16x32_bf16(
              af[i], bfr[j], acc[i][j], 0, 0, 0);
    }
  }

  // D[row=(lane>>4)*4+t][col=lane&15] per 16x16 fragment (HW-verified R4)
#pragma unroll
  for (int i = 0; i < 4; ++i) {
#pragma unroll
    for (int j = 0; j < 4; ++j) {
#pragma unroll
      for (int t = 0; t < 4; ++t) {
        const int mr = m0 + wm + i * 16 + kq * 4 + t;
        const int nc = n0 + wn + j * 16 + lr;
        const float val = acc[i][j][t];
        if constexpr (MODE == G_EMBED) {
          aux[(size_t)mr * 512 + nc] = f2bf(val);
        } else if constexpr (MODE == G_QKV) {
          aux[(size_t)mr * 1536 + nc] = f2bf(val);
        } else if constexpr (MODE == G_PROJ) {
          const float v2 =
              val + bf2f(resid[(size_t)mr * 512 + nc]) + bias[nc];
          aux[(size_t)mr * 512 + nc] = f2bf(v2);
        } else {  // OUTT: mr = channel, nc = token
          C[outBase + ((size_t)(nc >> 12)) * ((size_t)DIMn * Ln) +
            (size_t)mr * Ln + (nc & 4095)] = val;
        }
      }
    }
  }
}

// ---------------------------------------------------------------------------
// weight transpose + bf16 convert: in [K][N] f32 -> out [N][K] bf16
// ---------------------------------------------------------------------------
__global__ __launch_bounds__(256) void cvt_w(const float* __restrict__ in,
                                             ushort* __restrict__ out,
                                             int lgK, int N) {
  const int t = blockIdx.x * 256 + threadIdx.x;
  const int K = 1 << lgK;
  const int n = t >> lgK;
  const int k = t & (K - 1);
  out[t] = f2bf(in[(size_t)k * N + n]);
}

// x [B][256][4096] f32 -> xe [B*4096][256] bf16 (LDS tile transpose)
__global__ __launch_bounds__(256) void cvt_x(const float* __restrict__ x,
                                             ushort* __restrict__ xe) {
  __shared__ ushort tile[64][65];
  const int blk = blockIdx.x;
  const int lt = blk & 63;
  const int ct = (blk >> 6) & 3;
  const int b = blk >> 8;
  const int l0 = lt * 64, c0 = ct * 64;
  const int t = threadIdx.x;
  const int lanel = t & 63;
  const int grp = t >> 6;
#pragma unroll
  for (int it = 0; it < 16; ++it) {
    const int c = grp * 16 + it;
    tile[c][lanel] =
        f2bf(x[(size_t)b * (DIMn * Ln) + (size_t)(c0 + c) * Ln + l0 + lanel]);
  }
  __syncthreads();
#pragma unroll
  for (int it = 0; it < 16; ++it) {
    const int l = grp * 16 + it;
    xe[((size_t)b * Ln + l0 + l) * 256 + c0 + lanel] = tile[lanel][l];
  }
}

// ---------------------------------------------------------------------------
// LayerNorm: bf16 in [M][512], f32 stats, bf16 out (affine folded).
// ---------------------------------------------------------------------------
__global__ __launch_bounds__(128) void ln_fuse(const ushort* __restrict__ x2,
                                               const float* __restrict__ g1,
                                               const float* __restrict__ b1,
                                               ushort* __restrict__ xln) {
  const int row = blockIdx.x;
  const int t = threadIdx.x;
  const ushort4 u4 = *(const ushort4*)&x2[(size_t)row * 512 + t * 4];
  float v[4] = {bf2f(u4.x), bf2f(u4.y), bf2f(u4.z), bf2f(u4.w)};
  float s = v[0] + v[1] + v[2] + v[3];
  float s2 = v[0] * v[0] + v[1] * v[1] + v[2] * v[2] + v[3] * v[3];
#pragma unroll
  for (int off = 32; off > 0; off >>= 1) {
    s += __shfl_down(s, off);
    s2 += __shfl_down(s2, off);
  }
  __shared__ float red[4];
  if ((t & 63) == 0) {
    red[t >> 6] = s;
    red[2 + (t >> 6)] = s2;
  }
  __syncthreads();
  const float S = red[0] + red[1];
  const float S2 = red[2] + red[3];
  const float mu = S * (1.f / 512.f);
  const float rs = rsqrtf(S2 * (1.f / 512.f) - mu * mu + kEps);
  const float4 g = *(const float4*)&g1[t * 4];
  const float4 bb = *(const float4*)&b1[t * 4];
  ushort4 o;
  o.x = f2bf((v[0] - mu) * rs * g.x + bb.x);
  o.y = f2bf((v[1] - mu) * rs * g.y + bb.y);
  o.z = f2bf((v[2] - mu) * rs * g.z + bb.z);
  o.w = f2bf((v[3] - mu) * rs * g.w + bb.w);
  *(ushort4*)&xln[(size_t)row * 512 + t * 4] = o;
}

// ---------------------------------------------------------------------------
// Windowed attention + LePE (bf16 qkv in, f32 math, bf16 o out).
// Grid 1024 = (branch,b,win,head,rowhalf); 4x128-row K/V tiles in padded LDS.
// BUGFIX R7: cwS has 288 entries but block is 256 threads -> strided load
// (R2/R3/R6 left cwS[256..287] uninitialized => 0.35-0.44 absmax).
// ---------------------------------------------------------------------------
__global__ __launch_bounds__(256) void attn_k(
    const ushort* __restrict__ qkv, ushort* __restrict__ obf,
    const float* __restrict__ cw0, const float* __restrict__ cb0,
    const float* __restrict__ cw1, const float* __restrict__ cb1) {
  __shared__ float Ks[128][36];
  __shared__ float Vs[128][36];
  __shared__ float cwS[288];
  __shared__ float cbS[32];

  const int blk = blockIdx.x;
  const int half = blk & 1;
  const int head = (blk >> 1) & 7;
  const int win = (blk >> 4) & 7;
  const int b = (blk >> 7) & 3;
  const int branch = blk >> 9;
  const int tid = threadIdx.x;
  const int qcol = branch * CBn + head * HDn;

  const float* cw = branch ? cw1 : cw0;
  const float* cb = branch ? cb1 : cb0;
  for (int i = tid; i < 288; i += 256) cwS[i] = cw[head * 288 + i];
  if (tid < 32) cbS[tid] = cb[head * 32 + tid];

  auto tok2l = [&](int p) -> int {
    return branch == 0 ? ((p >> 3) * 64 + win * 8 + (p & 7)) : (win * 512 + p);
  };

  const int p = half * 256 + tid;
  float q[HDn];
  {
    const ushort* qrow = qkv + ((size_t)b * Ln + tok2l(p)) * 1536 + qcol;
#pragma unroll
    for (int g = 0; g < 4; ++g) {
      const bf16x8 u = *(const bf16x8*)(qrow + g * 8);
#pragma unroll
      for (int e = 0; e < 8; ++e)
        q[g * 8 + e] = bf2f((ushort)u[e]) * kScale;
    }
  }

  float accv[HDn] = {};
  float den = 0.f;
  const int r2 = tid >> 1;
  const int hf = tid & 1;

  for (int t = 0; t < 4; ++t) {
    __syncthreads();
    {
      const ushort* row =
          qkv + ((size_t)b * Ln + tok2l(t * 128 + r2)) * 1536 + qcol;
#pragma unroll
      for (int u = 0; u < 2; ++u) {
        const int d = hf * 16 + u * 8;
        const bf16x8 kk = *(const bf16x8*)(row + 512 + d);
        const bf16x8 vv = *(const bf16x8*)(row + 1024 + d);
#pragma unroll
        for (int e = 0; e < 8; ++e) {
          Ks[r2][d + e] = bf2f((ushort)kk[e]);
          Vs[r2][d + e] = bf2f((ushort)vv[e]);
        }
      }
    }
    __syncthreads();
    for (int j = 0; j < 128; ++j) {
      float s0 = 0.f, s1 = 0.f;
#pragma unroll
      for (int d4 = 0; d4 < 8; ++d4) {
        const float4 kv = *(const float4*)&Ks[j][d4 * 4];
        if (d4 & 1) {
          s1 = fmaf(q[d4 * 4 + 0], kv.x, s1);
          s1 = fmaf(q[d4 * 4 + 1], kv.y, s1);
          s1 = fmaf(q[d4 * 4 + 2], kv.z, s1);
          s1 = fmaf(q[d4 * 4 + 3], kv.w, s1);
        } else {
          s0 = fmaf(q[d4 * 4 + 0], kv.x, s0);
          s0 = fmaf(q[d4 * 4 + 1], kv.y, s0);
          s0 = fmaf(q[d4 * 4 + 2], kv.z, s0);
          s0 = fmaf(q[d4 * 4 + 3], kv.w, s0);
        }
      }
      const float e = __expf(s0 + s1);
      den += e;
#pragma unroll
      for (int d4 = 0; d4 < 8; ++d4) {
        const float4 vv = *(const float4*)&Vs[j][d4 * 4];
        accv[d4 * 4 + 0] = fmaf(e, vv.x, accv[d4 * 4 + 0]);
        accv[d4 * 4 + 1] = fmaf(e, vv.y, accv[d4 * 4 + 1]);
        accv[d4 * 4 + 2] = fmaf(e, vv.z, accv[d4 * 4 + 2]);
        accv[d4 * 4 + 3] = fmaf(e, vv.w, accv[d4 * 4 + 3]);
      }
    }
  }

  const int Hs = branch ? 8 : 64;
  const int Ws = branch ? 64 : 8;
  const int hl = branch ? (p >> 6) : (p >> 3);
  const int wl = branch ? (p & 63) : (p & 7);
  const float inv = 1.f / den;
  ushort* orow = obf + ((size_t)b * Ln + tok2l(p)) * 512 + qcol;

#pragma unroll
  for (int d4 = 0; d4 < 8; ++d4) {
    float le[4];
#pragma unroll
    for (int u = 0; u < 4; ++u) le[u] = cbS[d4 * 4 + u];
#pragma unroll
    for (int dh = -1; dh <= 1; ++dh) {
      const int hh = hl + dh;
      if (hh < 0 || hh >= Hs) continue;
#pragma unroll
      for (int dw = -1; dw <= 1; ++dw) {
        const int ww = wl + dw;
        if (ww < 0 || ww >= Ws) continue;
        const int l = branch ? (win * 512 + hh * 64 + ww)
                             : (hh * 64 + win * 8 + ww);
        const ushort4 vu = *(const ushort4*)(qkv +
                                             ((size_t)b * Ln + l) * 1536 +
                                             1024 + qcol + d4 * 4);
        const int wb = (dh + 1) * 3 + (dw + 1);
        le[0] = fmaf(bf2f(vu.x), cwS[(d4 * 4 + 0) * 9 + wb], le[0]);
        le[1] = fmaf(bf2f(vu.y), cwS[(d4 * 4 + 1) * 9 + wb], le[1]);
        le[2] = fmaf(bf2f(vu.z), cwS[(d4 * 4 + 2) * 9 + wb], le[2]);
        le[3] = fmaf(bf2f(vu.w), cwS[(d4 * 4 + 3) * 9 + wb], le[3]);
      }
    }
    ushort4 o4;
    o4.x = f2bf(fmaf(accv[d4 * 4 + 0], inv, le[0]));
    o4.y = f2bf(fmaf(accv[d4 * 4 + 1], inv, le[1]));
    o4.z = f2bf(fmaf(accv[d4 * 4 + 2], inv, le[2]));
    o4.w = f2bf(fmaf(accv[d4 * 4 + 3], inv, le[3]));
    *(ushort4*)&orow[d4 * 4] = o4;
  }
}

// ---------------------------------------------------------------------------
extern "C" void kernel_launch(void* const* d_in, const int* in_sizes, int n_in,
                              void* d_out, int out_size, void* d_ws,
                              size_t ws_size, hipStream_t stream) {
  const float* x = (const float*)d_in[0];
  const float* w_embed = (const float*)d_in[1];
  const float* g1 = (const float*)d_in[2];
  const float* b1 = (const float*)d_in[3];
  const float* w_qkv = (const float*)d_in[4];
  const float* cw0 = (const float*)d_in[5];
  const float* cb0 = (const float*)d_in[6];
  const float* cw1 = (const float*)d_in[7];
  const float* cb1 = (const float*)d_in[8];
  const float* w_proj = (const float*)d_in[9];
  const float* b_proj = (const float*)d_in[10];
  const float* w_out = (const float*)d_in[11];
  float* out = (float*)d_out;

  // carve (all bf16): x2 16.8M | qkv 50.3M | xe/o 16.8M | xln/xo 16.8M |
  // weights 2.6M => ~103 MB total (under R1's proven 134 MB watermark)
  char* p = (char*)d_ws;
  ushort* x2bf = (ushort*)p;
  p += (size_t)Mtot * 512 * 2;
  ushort* qkvbf = (ushort*)p;
  p += (size_t)Mtot * 1536 * 2;
  ushort* xe = (ushort*)p;  // [M][256]; later reused as o_bf16 [M][512]
  ushort* obf = (ushort*)p;
  p += (size_t)Mtot * 512 * 2;
  ushort* xln = (ushort*)p;  // [M][512]; later reused as xo_bf16
  ushort* xobf = (ushort*)p;
  p += (size_t)Mtot * 512 * 2;
  ushort* we_t = (ushort*)p;
  p += (size_t)512 * 256 * 2;
  ushort* wq_t = (ushort*)p;
  p += (size_t)1536 * 512 * 2;
  ushort* wp_t = (ushort*)p;
  p += (size_t)512 * 512 * 2;
  ushort* wo_t = (ushort*)p;

  cvt_w<<<dim3(512 * 256 / 256), 256, 0, stream>>>(w_embed, we_t, 8, 512);
  cvt_w<<<dim3(1536 * 512 / 256), 256, 0, stream>>>(w_qkv, wq_t, 9, 1536);
  cvt_w<<<dim3(512 * 512 / 256), 256, 0, stream>>>(w_proj, wp_t, 9, 512);
  cvt_w<<<dim3(256 * 512 / 256), 256, 0, stream>>>(w_out, wo_t, 9, 256);
  cvt_x<<<dim3(1024), 256, 0, stream>>>(x, xe);

  // 1) x2 = xe @ w_embed -> bf16
  gemm_bf<G_EMBED, 512, 256, 256><<<dim3(128 * 4), 256, 0, stream>>>(
      xe, we_t, nullptr, nullptr, nullptr, x2bf, 0);
  // 2) xln = LN(x2)
  ln_fuse<<<dim3(Mtot), 128, 0, stream>>>(x2bf, g1, b1, xln);
  // 3) qkv = xln @ w_qkv -> bf16
  gemm_bf<G_QKV, 1536, 512, 512><<<dim3(128 * 12), 256, 0, stream>>>(
      xln, wq_t, nullptr, nullptr, nullptr, qkvbf, 0);
  // 4) attention both branches -> o bf16 (overwrites xe region)
  attn_k<<<dim3(1024), 256, 0, stream>>>(qkvbf, obf, cw0, cb0, cw1, cb1);
  // 5) xo = x2 + o @ w_proj + b_proj -> bf16 (overwrites xln region)
  gemm_bf<G_PROJ, 512, 512, 512><<<dim3(128 * 4), 256, 0, stream>>>(
      obf, wp_t, nullptr, x2bf, b_proj, xobf, 0);
  // 6) out = w_out^T @ xo^T: direct [b][ch][l] store
  gemm_bf<G_OUTT, Mtot, 512, 512><<<dim3(2 * 128), 256, 0, stream>>>(
      wo_t, xobf, out, nullptr, nullptr, nullptr, 0);
  // 7) vout = w_out^T @ v^T (v read in-place from qkv, LDB=1536)
  gemm_bf<G_OUTT, Mtot, 512, 1536><<<dim3(2 * 128), 256, 0, stream>>>(
      wo_t, qkvbf + 1024, out, nullptr, nullptr, nullptr,
      (size_t)Bn * DIMn * Ln);
}

// Round 8
// 235.083 us; speedup vs baseline: 5.0862x; 2.1237x over previous
//
#include <hip/hip_runtime.h>
#include <cstdint>

#define Bn 4
#define DIMn 256
#define Ln 4096
#define C2n 512
#define CBn 256
#define HDn 32
#define Mtot (Bn * Ln)

using bf16x8 = __attribute__((ext_vector_type(8))) short;
using f32x4 = __attribute__((ext_vector_type(4))) float;

static constexpr float kScale = 0.17677669529663687f;  // 32^-0.5
static constexpr float kEps = 1e-5f;
static constexpr float kExpC = 0.17677669529663687f * 1.4426950408889634f;

__device__ __forceinline__ ushort f2bf(float f) {
  union {
    float f;
    unsigned u;
  } v;
  v.f = f;
  unsigned r = v.u + 0x7FFFu + ((v.u >> 16) & 1u);
  return (ushort)(r >> 16);
}

__device__ __forceinline__ float bf2f(ushort u) {
  union {
    unsigned u;
    float f;
  } v;
  v.u = (unsigned)u << 16;
  return v.f;
}

__device__ __forceinline__ void gload16(const void* g, void* l) {
  __builtin_amdgcn_global_load_lds(
      (const __attribute__((address_space(1))) unsigned*)g,
      (__attribute__((address_space(3))) unsigned*)l, 16, 0, 0);
}

// ---------------------------------------------------------------------------
// bf16 MFMA GEMM, m97 structure (HW-verified R4/R5): 128x128 tile, BK=64,
// 4 waves 2x2 of 64x64, 16x16x32 MFMA, linear LDS, gload16 staging.
// ---------------------------------------------------------------------------
enum { G_EMBED = 0, G_QKV = 1, G_PROJ = 2, G_OUTT = 3 };

template <int MODE, int ND, int KD, int LDB>
__global__ __launch_bounds__(256) void gemm_bf(
    const ushort* __restrict__ A, const ushort* __restrict__ Bt,
    float* __restrict__ C, const ushort* __restrict__ resid,
    const float* __restrict__ bias, ushort* __restrict__ aux,
    size_t outBase) {
  constexpr int NT = ND / 128;
  __shared__ ushort As[128 * 64];
  __shared__ ushort Bs[128 * 64];

  const int tid = threadIdx.x;
  const int wid = tid >> 6;
  const int lane = tid & 63;
  const int m0 = (blockIdx.x / NT) * 128;
  const int n0 = (blockIdx.x % NT) * 128;

  const int gs = (wid < 2) ? KD : LDB;
  const ushort* gsrc = (wid < 2)
                           ? A + (size_t)(m0 + (wid & 1) * 64) * KD
                           : Bt + (size_t)(n0 + (wid & 1) * 64) * LDB;
  ushort* lbase = (wid < 2 ? As : Bs) + (wid & 1) * (64 * 64);
  const int r8 = lane >> 3;
  const int c8 = lane & 7;

  f32x4 acc[4][4];
#pragma unroll
  for (int i = 0; i < 4; ++i)
#pragma unroll
    for (int j = 0; j < 4; ++j) acc[i][j] = (f32x4){0.f, 0.f, 0.f, 0.f};

  const int wm = (wid & 1) * 64;
  const int wn = (wid >> 1) * 64;
  const int lr = lane & 15;
  const int kq = lane >> 4;

  for (int k0 = 0; k0 < KD; k0 += 64) {
    __syncthreads();
#pragma unroll
    for (int i = 0; i < 8; ++i) {
      const ushort* g = gsrc + (size_t)(i * 8 + r8) * gs + (k0 + c8 * 8);
      gload16(g, lbase + i * 512);
    }
    __syncthreads();
#pragma unroll
    for (int kk = 0; kk < 2; ++kk) {
      bf16x8 af[4], bfr[4];
#pragma unroll
      for (int i = 0; i < 4; ++i)
        af[i] = *(const bf16x8*)(As + (wm + i * 16 + lr) * 64 +
                                 (kk * 4 + kq) * 8);
#pragma unroll
      for (int j = 0; j < 4; ++j)
        bfr[j] = *(const bf16x8*)(Bs + (wn + j * 16 + lr) * 64 +
                                  (kk * 4 + kq) * 8);
#pragma unroll
      for (int i = 0; i < 4; ++i)
#pragma unroll
        for (int j = 0; j < 4; ++j)
          acc[i][j] = __builtin_amdgcn_mfma_f32_16x16x32_bf16(
              af[i], bfr[j], acc[i][j], 0, 0, 0);
    }
  }

#pragma unroll
  for (int i = 0; i < 4; ++i) {
#pragma unroll
    for (int j = 0; j < 4; ++j) {
#pragma unroll
      for (int t = 0; t < 4; ++t) {
        const int mr = m0 + wm + i * 16 + kq * 4 + t;
        const int nc = n0 + wn + j * 16 + lr;
        const float val = acc[i][j][t];
        if constexpr (MODE == G_EMBED) {
          aux[(size_t)mr * 512 + nc] = f2bf(val);
        } else if constexpr (MODE == G_QKV) {
          aux[(size_t)mr * 1536 + nc] = f2bf(val);
        } else if constexpr (MODE == G_PROJ) {
          const float v2 =
              val + bf2f(resid[(size_t)mr * 512 + nc]) + bias[nc];
          aux[(size_t)mr * 512 + nc] = f2bf(v2);
        } else {  // OUTT: mr = channel, nc = token
          C[outBase + ((size_t)(nc >> 12)) * ((size_t)DIMn * Ln) +
            (size_t)mr * Ln + (nc & 4095)] = val;
        }
      }
    }
  }
}

// ---------------------------------------------------------------------------
__global__ __launch_bounds__(256) void cvt_w(const float* __restrict__ in,
                                             ushort* __restrict__ out,
                                             int lgK, int N) {
  const int t = blockIdx.x * 256 + threadIdx.x;
  const int K = 1 << lgK;
  const int n = t >> lgK;
  const int k = t & (K - 1);
  out[t] = f2bf(in[(size_t)k * N + n]);
}

__global__ __launch_bounds__(256) void cvt_x(const float* __restrict__ x,
                                             ushort* __restrict__ xe) {
  __shared__ ushort tile[64][65];
  const int blk = blockIdx.x;
  const int lt = blk & 63;
  const int ct = (blk >> 6) & 3;
  const int b = blk >> 8;
  const int l0 = lt * 64, c0 = ct * 64;
  const int t = threadIdx.x;
  const int lanel = t & 63;
  const int grp = t >> 6;
#pragma unroll
  for (int it = 0; it < 16; ++it) {
    const int c = grp * 16 + it;
    tile[c][lanel] =
        f2bf(x[(size_t)b * (DIMn * Ln) + (size_t)(c0 + c) * Ln + l0 + lanel]);
  }
  __syncthreads();
#pragma unroll
  for (int it = 0; it < 16; ++it) {
    const int l = grp * 16 + it;
    xe[((size_t)b * Ln + l0 + l) * 256 + c0 + lanel] = tile[lanel][l];
  }
}

__global__ __launch_bounds__(128) void ln_fuse(const ushort* __restrict__ x2,
                                               const float* __restrict__ g1,
                                               const float* __restrict__ b1,
                                               ushort* __restrict__ xln) {
  const int row = blockIdx.x;
  const int t = threadIdx.x;
  const ushort4 u4 = *(const ushort4*)&x2[(size_t)row * 512 + t * 4];
  float v[4] = {bf2f(u4.x), bf2f(u4.y), bf2f(u4.z), bf2f(u4.w)};
  float s = v[0] + v[1] + v[2] + v[3];
  float s2 = v[0] * v[0] + v[1] * v[1] + v[2] * v[2] + v[3] * v[3];
#pragma unroll
  for (int off = 32; off > 0; off >>= 1) {
    s += __shfl_down(s, off);
    s2 += __shfl_down(s2, off);
  }
  __shared__ float red[4];
  if ((t & 63) == 0) {
    red[t >> 6] = s;
    red[2 + (t >> 6)] = s2;
  }
  __syncthreads();
  const float S = red[0] + red[1];
  const float S2 = red[2] + red[3];
  const float mu = S * (1.f / 512.f);
  const float rs = rsqrtf(S2 * (1.f / 512.f) - mu * mu + kEps);
  const float4 g = *(const float4*)&g1[t * 4];
  const float4 bb = *(const float4*)&b1[t * 4];
  ushort4 o;
  o.x = f2bf((v[0] - mu) * rs * g.x + bb.x);
  o.y = f2bf((v[1] - mu) * rs * g.y + bb.y);
  o.z = f2bf((v[2] - mu) * rs * g.z + bb.z);
  o.w = f2bf((v[3] - mu) * rs * g.w + bb.w);
  *(ushort4*)&xln[(size_t)row * 512 + t * 4] = o;
}

// ---------------------------------------------------------------------------
// MFMA attention + LePE. Block = (branch,b,win,head), 4 waves x 128 q-rows.
// Per 32-key tile: K [32][40] LDS; S = mfma(Q,K) (C=A.B^T, proven layout);
// exp2f on VALU (== __expf(s*scale), no max-sub: proven R1-R7); P bf16 into
// per-wave LDS [128][40]; PV = mfma(P, Vt) with Vt[32][520] whole-window
// transposed V (also feeds LePE taps from LDS). den: per-lane partials +
// one shfl_xor butterfly over the lr-group (lands in the D-layout lanes).
// ---------------------------------------------------------------------------
__global__ __launch_bounds__(256, 2) void attn_m(
    const ushort* __restrict__ qkv, ushort* __restrict__ obf,
    const float* __restrict__ cw0, const float* __restrict__ cb0,
    const float* __restrict__ cw1, const float* __restrict__ cb1) {
  __shared__ ushort VtS[32 * 520];       // 33,280 B
  __shared__ ushort KsS[32 * 40];        //  2,560 B
  __shared__ ushort PsS[4 * 128 * 40];   // 40,960 B
  __shared__ float cwS[288];
  __shared__ float cbS[32];

  const int blk = blockIdx.x;
  const int branch = blk >> 8;
  const int b = (blk >> 6) & 3;
  const int win = (blk >> 3) & 7;
  const int head = blk & 7;
  const int tid = threadIdx.x;
  const int w = tid >> 6;
  const int lane = tid & 63;
  const int lr = lane & 15;
  const int kq = lane >> 4;
  const int qcol = branch * CBn + head * HDn;

  const float* cw = branch ? cw1 : cw0;
  const float* cb = branch ? cb1 : cb0;
  for (int i = tid; i < 288; i += 256) cwS[i] = cw[head * 288 + i];
  if (tid < 32) cbS[tid] = cb[head * 32 + tid];

  auto tok2l = [&](int p) -> int {
    return branch == 0 ? ((p >> 3) * 64 + win * 8 + (p & 7)) : (win * 512 + p);
  };
  const size_t rowbase = (size_t)b * Ln;

  // ---- stage Vt[d][p] = v[p][d], rows padded to 520 ----
#pragma unroll
  for (int rr = 0; rr < 2; ++rr) {
    const int j = tid + rr * 256;
    const ushort* vrow = qkv + (rowbase + tok2l(j)) * 1536 + 1024 + qcol;
#pragma unroll
    for (int g = 0; g < 4; ++g) {
      const bf16x8 u = *(const bf16x8*)(vrow + g * 8);
#pragma unroll
      for (int e = 0; e < 8; ++e)
        VtS[(g * 8 + e) * 520 + j] = (ushort)u[e];
    }
  }

  // ---- preload Q A-frags for this wave's 128 q-rows ----
  bf16x8 qf[8];
#pragma unroll
  for (int qt = 0; qt < 8; ++qt) {
    const int p = w * 128 + qt * 16 + lr;
    qf[qt] =
        *(const bf16x8*)(qkv + (rowbase + tok2l(p)) * 1536 + qcol + kq * 8);
  }

  f32x4 acc[8][2];
#pragma unroll
  for (int qt = 0; qt < 8; ++qt) {
    acc[qt][0] = (f32x4){0.f, 0.f, 0.f, 0.f};
    acc[qt][1] = (f32x4){0.f, 0.f, 0.f, 0.f};
  }
  float den[8][4] = {};
  ushort* Pw = PsS + w * (128 * 40);
  const f32x4 zero4 = (f32x4){0.f, 0.f, 0.f, 0.f};

  for (int kt = 0; kt < 16; ++kt) {
    const int k0 = kt * 32;
    __syncthreads();
    // stage K tile [32][40]: thread -> key tid>>3, 4 ch at (tid&7)*4
    {
      const int key = tid >> 3;
      const int d0 = (tid & 7) * 4;
      const ushort4 k4 = *(const ushort4*)(qkv +
                                           (rowbase + tok2l(k0 + key)) * 1536 +
                                           512 + qcol + d0);
      *(ushort4*)&KsS[key * 40 + d0] = k4;
    }
    __syncthreads();

    const bf16x8 kf0 = *(const bf16x8*)&KsS[lr * 40 + kq * 8];
    const bf16x8 kf1 = *(const bf16x8*)&KsS[(16 + lr) * 40 + kq * 8];

#pragma unroll
    for (int qt = 0; qt < 8; ++qt) {
      const f32x4 s0 =
          __builtin_amdgcn_mfma_f32_16x16x32_bf16(qf[qt], kf0, zero4, 0, 0, 0);
      const f32x4 s1 =
          __builtin_amdgcn_mfma_f32_16x16x32_bf16(qf[qt], kf1, zero4, 0, 0, 0);
#pragma unroll
      for (int t = 0; t < 4; ++t) {
        const float e0 = exp2f(s0[t] * kExpC);
        const float e1 = exp2f(s1[t] * kExpC);
        den[qt][t] += e0 + e1;
        const int prow = (qt * 16 + kq * 4 + t) * 40;
        Pw[prow + lr] = f2bf(e0);
        Pw[prow + 16 + lr] = f2bf(e1);
      }
    }
    asm volatile("s_waitcnt lgkmcnt(0)" ::: "memory");
    __builtin_amdgcn_sched_barrier(0);

    const bf16x8 vf0 = *(const bf16x8*)&VtS[lr * 520 + k0 + kq * 8];
    const bf16x8 vf1 = *(const bf16x8*)&VtS[(16 + lr) * 520 + k0 + kq * 8];
#pragma unroll
    for (int qt = 0; qt < 8; ++qt) {
      const bf16x8 pf = *(const bf16x8*)&Pw[(qt * 16 + lr) * 40 + kq * 8];
      acc[qt][0] =
          __builtin_amdgcn_mfma_f32_16x16x32_bf16(pf, vf0, acc[qt][0], 0, 0, 0);
      acc[qt][1] =
          __builtin_amdgcn_mfma_f32_16x16x32_bf16(pf, vf1, acc[qt][1], 0, 0, 0);
    }
  }

  // ---- den butterfly within lr-group (masks < 16 stay in-group) ----
#pragma unroll
  for (int qt = 0; qt < 8; ++qt)
#pragma unroll
    for (int t = 0; t < 4; ++t) {
      float d = den[qt][t];
      d += __shfl_xor(d, 1);
      d += __shfl_xor(d, 2);
      d += __shfl_xor(d, 4);
      d += __shfl_xor(d, 8);
      den[qt][t] = d;
    }

  // ---- epilogue: O = PV/den + LePE(Vt), write bf16 ----
  const int Hs = branch ? 8 : 64;
  const int Ws = branch ? 64 : 8;
#pragma unroll
  for (int qt = 0; qt < 8; ++qt) {
#pragma unroll
    for (int t = 0; t < 4; ++t) {
      const int p = w * 128 + qt * 16 + kq * 4 + t;
      const int l = tok2l(p);
      const int hl = branch ? (p >> 6) : (p >> 3);
      const int wl = branch ? (p & 63) : (p & 7);
      const float inv = 1.f / den[qt][t];
      ushort* orow = obf + ((size_t)b * Ln + l) * 512 + qcol;
#pragma unroll
      for (int dt = 0; dt < 2; ++dt) {
        const int d = dt * 16 + lr;
        float le = cbS[d];
#pragma unroll
        for (int dh = -1; dh <= 1; ++dh) {
          const int hh = hl + dh;
          if (hh < 0 || hh >= Hs) continue;
#pragma unroll
          for (int dw = -1; dw <= 1; ++dw) {
            const int ww = wl + dw;
            if (ww < 0 || ww >= Ws) continue;
            const int pp = hh * Ws + ww;
            le = fmaf(bf2f(VtS[d * 520 + pp]),
                      cwS[d * 9 + (dh + 1) * 3 + (dw + 1)], le);
          }
        }
        orow[d] = f2bf(fmaf(acc[qt][dt][t], inv, le));
      }
    }
  }
}

// ---------------------------------------------------------------------------
extern "C" void kernel_launch(void* const* d_in, const int* in_sizes, int n_in,
                              void* d_out, int out_size, void* d_ws,
                              size_t ws_size, hipStream_t stream) {
  const float* x = (const float*)d_in[0];
  const float* w_embed = (const float*)d_in[1];
  const float* g1 = (const float*)d_in[2];
  const float* b1 = (const float*)d_in[3];
  const float* w_qkv = (const float*)d_in[4];
  const float* cw0 = (const float*)d_in[5];
  const float* cb0 = (const float*)d_in[6];
  const float* cw1 = (const float*)d_in[7];
  const float* cb1 = (const float*)d_in[8];
  const float* w_proj = (const float*)d_in[9];
  const float* b_proj = (const float*)d_in[10];
  const float* w_out = (const float*)d_in[11];
  float* out = (float*)d_out;

  char* p = (char*)d_ws;
  ushort* x2bf = (ushort*)p;
  p += (size_t)Mtot * 512 * 2;
  ushort* qkvbf = (ushort*)p;
  p += (size_t)Mtot * 1536 * 2;
  ushort* xe = (ushort*)p;  // [M][256]; later reused as o_bf16 [M][512]
  ushort* obf = (ushort*)p;
  p += (size_t)Mtot * 512 * 2;
  ushort* xln = (ushort*)p;  // [M][512]; later reused as xo_bf16
  ushort* xobf = (ushort*)p;
  p += (size_t)Mtot * 512 * 2;
  ushort* we_t = (ushort*)p;
  p += (size_t)512 * 256 * 2;
  ushort* wq_t = (ushort*)p;
  p += (size_t)1536 * 512 * 2;
  ushort* wp_t = (ushort*)p;
  p += (size_t)512 * 512 * 2;
  ushort* wo_t = (ushort*)p;

  cvt_w<<<dim3(512 * 256 / 256), 256, 0, stream>>>(w_embed, we_t, 8, 512);
  cvt_w<<<dim3(1536 * 512 / 256), 256, 0, stream>>>(w_qkv, wq_t, 9, 1536);
  cvt_w<<<dim3(512 * 512 / 256), 256, 0, stream>>>(w_proj, wp_t, 9, 512);
  cvt_w<<<dim3(256 * 512 / 256), 256, 0, stream>>>(w_out, wo_t, 9, 256);
  cvt_x<<<dim3(1024), 256, 0, stream>>>(x, xe);

  gemm_bf<G_EMBED, 512, 256, 256><<<dim3(128 * 4), 256, 0, stream>>>(
      xe, we_t, nullptr, nullptr, nullptr, x2bf, 0);
  ln_fuse<<<dim3(Mtot), 128, 0, stream>>>(x2bf, g1, b1, xln);
  gemm_bf<G_QKV, 1536, 512, 512><<<dim3(128 * 12), 256, 0, stream>>>(
      xln, wq_t, nullptr, nullptr, nullptr, qkvbf, 0);
  attn_m<<<dim3(512), 256, 0, stream>>>(qkvbf, obf, cw0, cb0, cw1, cb1);
  gemm_bf<G_PROJ, 512, 512, 512><<<dim3(128 * 4), 256, 0, stream>>>(
      obf, wp_t, nullptr, x2bf, b_proj, xobf, 0);
  gemm_bf<G_OUTT, Mtot, 512, 512><<<dim3(2 * 128), 256, 0, stream>>>(
      wo_t, xobf, out, nullptr, nullptr, nullptr, 0);
  gemm_bf<G_OUTT, Mtot, 512, 1536><<<dim3(2 * 128), 256, 0, stream>>>(
      wo_t, qkvbf + 1024, out, nullptr, nullptr, nullptr,
      (size_t)Bn * DIMn * Ln);
}

// Round 9
// 192.919 us; speedup vs baseline: 6.1979x; 1.2186x over previous
//
#include <hip/hip_runtime.h>
#include <cstdint>

#define Bn 4
#define DIMn 256
#define Ln 4096
#define C2n 512
#define CBn 256
#define HDn 32
#define Mtot (Bn * Ln)

using bf16x8 = __attribute__((ext_vector_type(8))) short;
using f32x4 = __attribute__((ext_vector_type(4))) float;

static constexpr float kScale = 0.17677669529663687f;  // 32^-0.5
static constexpr float kEps = 1e-5f;
static constexpr float kExpC = 0.17677669529663687f * 1.4426950408889634f;

__device__ __forceinline__ ushort f2bf(float f) {
  union {
    float f;
    unsigned u;
  } v;
  v.f = f;
  unsigned r = v.u + 0x7FFFu + ((v.u >> 16) & 1u);
  return (ushort)(r >> 16);
}

__device__ __forceinline__ float bf2f(ushort u) {
  union {
    unsigned u;
    float f;
  } v;
  v.u = (unsigned)u << 16;
  return v.f;
}

// packed 2xf32 -> 2xbf16 (RNE), src0 -> low half [T12 primitive, m240]
__device__ __forceinline__ unsigned cvtpk(float lo, float hi) {
  unsigned r;
  asm("v_cvt_pk_bf16_f32 %0, %1, %2" : "=v"(r) : "v"(lo), "v"(hi));
  return r;
}

__device__ __forceinline__ void gload16(const void* g, void* l) {
  __builtin_amdgcn_global_load_lds(
      (const __attribute__((address_space(1))) unsigned*)g,
      (__attribute__((address_space(3))) unsigned*)l, 16, 0, 0);
}

// ---------------------------------------------------------------------------
// bf16 MFMA GEMM, m97 structure (HW-verified R4/R5): 128x128 tile, BK=64,
// 4 waves 2x2 of 64x64, 16x16x32 MFMA, linear LDS, gload16 staging.
// ---------------------------------------------------------------------------
enum { G_EMBED = 0, G_QKV = 1, G_PROJ = 2, G_OUTT = 3 };

template <int MODE, int ND, int KD, int LDB>
__global__ __launch_bounds__(256) void gemm_bf(
    const ushort* __restrict__ A, const ushort* __restrict__ Bt,
    float* __restrict__ C, const ushort* __restrict__ resid,
    const float* __restrict__ bias, ushort* __restrict__ aux,
    size_t outBase) {
  constexpr int NT = ND / 128;
  __shared__ ushort As[128 * 64];
  __shared__ ushort Bs[128 * 64];

  const int tid = threadIdx.x;
  const int wid = tid >> 6;
  const int lane = tid & 63;
  const int m0 = (blockIdx.x / NT) * 128;
  const int n0 = (blockIdx.x % NT) * 128;

  const int gs = (wid < 2) ? KD : LDB;
  const ushort* gsrc = (wid < 2)
                           ? A + (size_t)(m0 + (wid & 1) * 64) * KD
                           : Bt + (size_t)(n0 + (wid & 1) * 64) * LDB;
  ushort* lbase = (wid < 2 ? As : Bs) + (wid & 1) * (64 * 64);
  const int r8 = lane >> 3;
  const int c8 = lane & 7;

  f32x4 acc[4][4];
#pragma unroll
  for (int i = 0; i < 4; ++i)
#pragma unroll
    for (int j = 0; j < 4; ++j) acc[i][j] = (f32x4){0.f, 0.f, 0.f, 0.f};

  const int wm = (wid & 1) * 64;
  const int wn = (wid >> 1) * 64;
  const int lr = lane & 15;
  const int kq = lane >> 4;

  for (int k0 = 0; k0 < KD; k0 += 64) {
    __syncthreads();
#pragma unroll
    for (int i = 0; i < 8; ++i) {
      const ushort* g = gsrc + (size_t)(i * 8 + r8) * gs + (k0 + c8 * 8);
      gload16(g, lbase + i * 512);
    }
    __syncthreads();
#pragma unroll
    for (int kk = 0; kk < 2; ++kk) {
      bf16x8 af[4], bfr[4];
#pragma unroll
      for (int i = 0; i < 4; ++i)
        af[i] = *(const bf16x8*)(As + (wm + i * 16 + lr) * 64 +
                                 (kk * 4 + kq) * 8);
#pragma unroll
      for (int j = 0; j < 4; ++j)
        bfr[j] = *(const bf16x8*)(Bs + (wn + j * 16 + lr) * 64 +
                                  (kk * 4 + kq) * 8);
#pragma unroll
      for (int i = 0; i < 4; ++i)
#pragma unroll
        for (int j = 0; j < 4; ++j)
          acc[i][j] = __builtin_amdgcn_mfma_f32_16x16x32_bf16(
              af[i], bfr[j], acc[i][j], 0, 0, 0);
    }
  }

#pragma unroll
  for (int i = 0; i < 4; ++i) {
#pragma unroll
    for (int j = 0; j < 4; ++j) {
#pragma unroll
      for (int t = 0; t < 4; ++t) {
        const int mr = m0 + wm + i * 16 + kq * 4 + t;
        const int nc = n0 + wn + j * 16 + lr;
        float val = acc[i][j][t];
        if constexpr (MODE == G_EMBED) {
          aux[(size_t)mr * 512 + nc] = f2bf(val);
        } else if constexpr (MODE == G_QKV) {
          // fold softmax scale*log2e into q columns (cols 0-511 are q)
          if (nc < 512) val *= kExpC;
          aux[(size_t)mr * 1536 + nc] = f2bf(val);
        } else if constexpr (MODE == G_PROJ) {
          const float v2 =
              val + bf2f(resid[(size_t)mr * 512 + nc]) + bias[nc];
          aux[(size_t)mr * 512 + nc] = f2bf(v2);
        } else {  // OUTT: mr = channel, nc = token
          C[outBase + ((size_t)(nc >> 12)) * ((size_t)DIMn * Ln) +
            (size_t)mr * Ln + (nc & 4095)] = val;
        }
      }
    }
  }
}

// ---------------------------------------------------------------------------
__global__ __launch_bounds__(256) void cvt_w(const float* __restrict__ in,
                                             ushort* __restrict__ out,
                                             int lgK, int N) {
  const int t = blockIdx.x * 256 + threadIdx.x;
  const int K = 1 << lgK;
  const int n = t >> lgK;
  const int k = t & (K - 1);
  out[t] = f2bf(in[(size_t)k * N + n]);
}

__global__ __launch_bounds__(256) void cvt_x(const float* __restrict__ x,
                                             ushort* __restrict__ xe) {
  __shared__ ushort tile[64][65];
  const int blk = blockIdx.x;
  const int lt = blk & 63;
  const int ct = (blk >> 6) & 3;
  const int b = blk >> 8;
  const int l0 = lt * 64, c0 = ct * 64;
  const int t = threadIdx.x;
  const int lanel = t & 63;
  const int grp = t >> 6;
#pragma unroll
  for (int it = 0; it < 16; ++it) {
    const int c = grp * 16 + it;
    tile[c][lanel] =
        f2bf(x[(size_t)b * (DIMn * Ln) + (size_t)(c0 + c) * Ln + l0 + lanel]);
  }
  __syncthreads();
#pragma unroll
  for (int it = 0; it < 16; ++it) {
    const int l = grp * 16 + it;
    xe[((size_t)b * Ln + l0 + l) * 256 + c0 + lanel] = tile[lanel][l];
  }
}

__global__ __launch_bounds__(128) void ln_fuse(const ushort* __restrict__ x2,
                                               const float* __restrict__ g1,
                                               const float* __restrict__ b1,
                                               ushort* __restrict__ xln) {
  const int row = blockIdx.x;
  const int t = threadIdx.x;
  const ushort4 u4 = *(const ushort4*)&x2[(size_t)row * 512 + t * 4];
  float v[4] = {bf2f(u4.x), bf2f(u4.y), bf2f(u4.z), bf2f(u4.w)};
  float s = v[0] + v[1] + v[2] + v[3];
  float s2 = v[0] * v[0] + v[1] * v[1] + v[2] * v[2] + v[3] * v[3];
#pragma unroll
  for (int off = 32; off > 0; off >>= 1) {
    s += __shfl_down(s, off);
    s2 += __shfl_down(s2, off);
  }
  __shared__ float red[4];
  if ((t & 63) == 0) {
    red[t >> 6] = s;
    red[2 + (t >> 6)] = s2;
  }
  __syncthreads();
  const float S = red[0] + red[1];
  const float S2 = red[2] + red[3];
  const float mu = S * (1.f / 512.f);
  const float rs = rsqrtf(S2 * (1.f / 512.f) - mu * mu + kEps);
  const float4 g = *(const float4*)&g1[t * 4];
  const float4 bb = *(const float4*)&b1[t * 4];
  ushort4 o;
  o.x = f2bf((v[0] - mu) * rs * g.x + bb.x);
  o.y = f2bf((v[1] - mu) * rs * g.y + bb.y);
  o.z = f2bf((v[2] - mu) * rs * g.z + bb.z);
  o.w = f2bf((v[3] - mu) * rs * g.w + bb.w);
  *(ushort4*)&xln[(size_t)row * 512 + t * 4] = o;
}

// ---------------------------------------------------------------------------
// MFMA attention + LePE, lane-local softmax (swapped QK^T + key permutation).
// Block = (branch,b,win,head,qhalf): 1024 blocks x 4 waves x 64 q-rows.
// mfma(K,Q) puts S[q=lr][keys] in-lane; K staged with key j at tile (j>>2)&1,
// row (j>>3)*4+(j&3) so the 8 in-lane exps ARE the PV A-frag (keys kq*8..+7)
// -- softmax has zero LDS / zero cross-lane ops. q pre-scaled by kExpC in
// the QKV epilogue. den: per-lane partials + shfl_xor(16,32) + denS bounce.
// ---------------------------------------------------------------------------
__global__ __launch_bounds__(256, 4) void attn_m(
    const ushort* __restrict__ qkv, ushort* __restrict__ obf,
    const float* __restrict__ cw0, const float* __restrict__ cb0,
    const float* __restrict__ cw1, const float* __restrict__ cb1) {
  __shared__ ushort VtS[32 * 520];  // 33,280 B  Vt[d][token], identity order
  __shared__ ushort KsS[32 * 40];   //  2,560 B  permuted key tiles
  __shared__ float denS[4 * 64];    //  1,024 B
  __shared__ float cwS[288];
  __shared__ float cbS[32];

  const int blk = blockIdx.x;
  const int branch = blk >> 9;
  const int b = (blk >> 7) & 3;
  const int win = (blk >> 4) & 7;
  const int head = (blk >> 1) & 7;
  const int qh = blk & 1;
  const int tid = threadIdx.x;
  const int w = tid >> 6;
  const int lane = tid & 63;
  const int lr = lane & 15;
  const int kq = lane >> 4;
  const int qcol = branch * CBn + head * HDn;

  const float* cw = branch ? cw1 : cw0;
  const float* cb = branch ? cb1 : cb0;
  for (int i = tid; i < 288; i += 256) cwS[i] = cw[head * 288 + i];
  if (tid < 32) cbS[tid] = cb[head * 32 + tid];

  auto tok2l = [&](int p) -> int {
    return branch == 0 ? ((p >> 3) * 64 + win * 8 + (p & 7)) : (win * 512 + p);
  };
  const size_t rowbase = (size_t)b * Ln;

  // ---- stage Vt[d][p] (identity token order, rows padded to 520) ----
#pragma unroll
  for (int rr = 0; rr < 2; ++rr) {
    const int j = tid + rr * 256;
    const ushort* vrow = qkv + (rowbase + tok2l(j)) * 1536 + 1024 + qcol;
#pragma unroll
    for (int g = 0; g < 4; ++g) {
      const bf16x8 u = *(const bf16x8*)(vrow + g * 8);
#pragma unroll
      for (int e = 0; e < 8; ++e)
        VtS[(g * 8 + e) * 520 + j] = (ushort)u[e];
    }
  }

  // ---- preload Q B-frags for this wave's 64 q-rows (pre-scaled) ----
  bf16x8 qf[4];
#pragma unroll
  for (int qt = 0; qt < 4; ++qt) {
    const int p = qh * 256 + w * 64 + qt * 16 + lr;
    qf[qt] =
        *(const bf16x8*)(qkv + (rowbase + tok2l(p)) * 1536 + qcol + kq * 8);
  }

  f32x4 acc[4][2];
#pragma unroll
  for (int qt = 0; qt < 4; ++qt) {
    acc[qt][0] = (f32x4){0.f, 0.f, 0.f, 0.f};
    acc[qt][1] = (f32x4){0.f, 0.f, 0.f, 0.f};
  }
  float den[4] = {};
  const f32x4 zero4 = (f32x4){0.f, 0.f, 0.f, 0.f};

  for (int kt = 0; kt < 16; ++kt) {
    const int k0 = kt * 32;
    __syncthreads();
    // stage K tile, PERMUTED: key j -> tile (j>>2)&1, row (j>>3)*4+(j&3)
    {
      const int j = tid >> 3;
      const int d0 = (tid & 7) * 4;
      const int row = ((j >> 2) & 1) * 16 + (j >> 3) * 4 + (j & 3);
      const ushort4 k4 = *(const ushort4*)(qkv +
                                           (rowbase + tok2l(k0 + j)) * 1536 +
                                           512 + qcol + d0);
      *(ushort4*)&KsS[row * 40 + d0] = k4;
    }
    __syncthreads();

    const bf16x8 kf0 = *(const bf16x8*)&KsS[lr * 40 + kq * 8];
    const bf16x8 kf1 = *(const bf16x8*)&KsS[(16 + lr) * 40 + kq * 8];
    const bf16x8 vf0 = *(const bf16x8*)&VtS[lr * 520 + k0 + kq * 8];
    const bf16x8 vf1 = *(const bf16x8*)&VtS[(16 + lr) * 520 + k0 + kq * 8];

#pragma unroll
    for (int qt = 0; qt < 4; ++qt) {
      // swapped: S[q=lr][key] lands in-lane
      const f32x4 s0 =
          __builtin_amdgcn_mfma_f32_16x16x32_bf16(kf0, qf[qt], zero4, 0, 0, 0);
      const f32x4 s1 =
          __builtin_amdgcn_mfma_f32_16x16x32_bf16(kf1, qf[qt], zero4, 0, 0, 0);
      float e0[4], e1[4];
#pragma unroll
      for (int t = 0; t < 4; ++t) {
        e0[t] = __builtin_amdgcn_exp2f(s0[t]);
        e1[t] = __builtin_amdgcn_exp2f(s1[t]);
      }
      den[qt] += (e0[0] + e0[1] + e0[2] + e0[3]) +
                 (e1[0] + e1[1] + e1[2] + e1[3]);
      union {
        unsigned u[4];
        bf16x8 v;
      } pa;
      pa.u[0] = cvtpk(e0[0], e0[1]);
      pa.u[1] = cvtpk(e0[2], e0[3]);
      pa.u[2] = cvtpk(e1[0], e1[1]);
      pa.u[3] = cvtpk(e1[2], e1[3]);
      acc[qt][0] = __builtin_amdgcn_mfma_f32_16x16x32_bf16(pa.v, vf0,
                                                           acc[qt][0], 0, 0, 0);
      acc[qt][1] = __builtin_amdgcn_mfma_f32_16x16x32_bf16(pa.v, vf1,
                                                           acc[qt][1], 0, 0, 0);
    }
  }

  // ---- den: reduce across kq lanes, bounce through per-wave LDS ----
#pragma unroll
  for (int qt = 0; qt < 4; ++qt) {
    float d = den[qt];
    d += __shfl_xor(d, 16);
    d += __shfl_xor(d, 32);
    if (lane < 16) denS[w * 64 + qt * 16 + lr] = d;
  }
  __syncthreads();

  // ---- epilogue: O = PV/den + LePE(Vt), write bf16 ----
  const int Hs = branch ? 8 : 64;
  const int Ws = branch ? 64 : 8;
#pragma unroll
  for (int qt = 0; qt < 4; ++qt) {
#pragma unroll
    for (int t = 0; t < 4; ++t) {
      const int p = qh * 256 + w * 64 + qt * 16 + kq * 4 + t;
      const int l = tok2l(p);
      const int hl = branch ? (p >> 6) : (p >> 3);
      const int wl = branch ? (p & 63) : (p & 7);
      const float inv = 1.f / denS[w * 64 + qt * 16 + kq * 4 + t];
      ushort* orow = obf + ((size_t)b * Ln + l) * 512 + qcol;
#pragma unroll
      for (int dt = 0; dt < 2; ++dt) {
        const int d = dt * 16 + lr;
        float le = cbS[d];
#pragma unroll
        for (int dh = -1; dh <= 1; ++dh) {
          const int hh = hl + dh;
          if (hh < 0 || hh >= Hs) continue;
#pragma unroll
          for (int dw = -1; dw <= 1; ++dw) {
            const int ww = wl + dw;
            if (ww < 0 || ww >= Ws) continue;
            const int pp = hh * Ws + ww;
            le = fmaf(bf2f(VtS[d * 520 + pp]),
                      cwS[d * 9 + (dh + 1) * 3 + (dw + 1)], le);
          }
        }
        orow[d] = f2bf(fmaf(acc[qt][dt][t], inv, le));
      }
    }
  }
}

// ---------------------------------------------------------------------------
extern "C" void kernel_launch(void* const* d_in, const int* in_sizes, int n_in,
                              void* d_out, int out_size, void* d_ws,
                              size_t ws_size, hipStream_t stream) {
  const float* x = (const float*)d_in[0];
  const float* w_embed = (const float*)d_in[1];
  const float* g1 = (const float*)d_in[2];
  const float* b1 = (const float*)d_in[3];
  const float* w_qkv = (const float*)d_in[4];
  const float* cw0 = (const float*)d_in[5];
  const float* cb0 = (const float*)d_in[6];
  const float* cw1 = (const float*)d_in[7];
  const float* cb1 = (const float*)d_in[8];
  const float* w_proj = (const float*)d_in[9];
  const float* b_proj = (const float*)d_in[10];
  const float* w_out = (const float*)d_in[11];
  float* out = (float*)d_out;

  char* p = (char*)d_ws;
  ushort* x2bf = (ushort*)p;
  p += (size_t)Mtot * 512 * 2;
  ushort* qkvbf = (ushort*)p;
  p += (size_t)Mtot * 1536 * 2;
  ushort* xe = (ushort*)p;  // [M][256]; later reused as o_bf16 [M][512]
  ushort* obf = (ushort*)p;
  p += (size_t)Mtot * 512 * 2;
  ushort* xln = (ushort*)p;  // [M][512]; later reused as xo_bf16
  ushort* xobf = (ushort*)p;
  p += (size_t)Mtot * 512 * 2;
  ushort* we_t = (ushort*)p;
  p += (size_t)512 * 256 * 2;
  ushort* wq_t = (ushort*)p;
  p += (size_t)1536 * 512 * 2;
  ushort* wp_t = (ushort*)p;
  p += (size_t)512 * 512 * 2;
  ushort* wo_t = (ushort*)p;

  cvt_w<<<dim3(512 * 256 / 256), 256, 0, stream>>>(w_embed, we_t, 8, 512);
  cvt_w<<<dim3(1536 * 512 / 256), 256, 0, stream>>>(w_qkv, wq_t, 9, 1536);
  cvt_w<<<dim3(512 * 512 / 256), 256, 0, stream>>>(w_proj, wp_t, 9, 512);
  cvt_w<<<dim3(256 * 512 / 256), 256, 0, stream>>>(w_out, wo_t, 9, 256);
  cvt_x<<<dim3(1024), 256, 0, stream>>>(x, xe);

  gemm_bf<G_EMBED, 512, 256, 256><<<dim3(128 * 4), 256, 0, stream>>>(
      xe, we_t, nullptr, nullptr, nullptr, x2bf, 0);
  ln_fuse<<<dim3(Mtot), 128, 0, stream>>>(x2bf, g1, b1, xln);
  gemm_bf<G_QKV, 1536, 512, 512><<<dim3(128 * 12), 256, 0, stream>>>(
      xln, wq_t, nullptr, nullptr, nullptr, qkvbf, 0);
  attn_m<<<dim3(1024), 256, 0, stream>>>(qkvbf, obf, cw0, cb0, cw1, cb1);
  gemm_bf<G_PROJ, 512, 512, 512><<<dim3(128 * 4), 256, 0, stream>>>(
      obf, wp_t, nullptr, x2bf, b_proj, xobf, 0);
  gemm_bf<G_OUTT, Mtot, 512, 512><<<dim3(2 * 128), 256, 0, stream>>>(
      wo_t, xobf, out, nullptr, nullptr, nullptr, 0);
  gemm_bf<G_OUTT, Mtot, 512, 1536><<<dim3(2 * 128), 256, 0, stream>>>(
      wo_t, qkvbf + 1024, out, nullptr, nullptr, nullptr,
      (size_t)Bn * DIMn * Ln);
}